// Round 9
// baseline (936.487 us; speedup 1.0000x reference)
//
#include <hip/hip_runtime.h>
#include <cstdint>
#include <cstddef>

#define NPOINT 512
#define NSAMPLE 32
#define NPB 8192  // points per batch

// Inputs: float32. Outputs: float32 flat concat (new_xyz, new_idx,
// new_features, sample_ids). Selection math (FPS argmax, ball d2<r2) must be
// bit-exact vs numpy f32: __f*_rn ops, no FMA contraction, exact tie-breaks.
__device__ __forceinline__ unsigned short f2bf(float f) {
  unsigned int u = __float_as_uint(f);
  unsigned int r = u + 0x7FFFu + ((u >> 16) & 1u);  // RNE
  return (unsigned short)(r >> 16);
}

// ---------------------------------------------------------------- FPS
// r5-r8 lesson: the allocator pins this kernel at ~64 VGPR (max occupancy)
// and will remat (r5/r6) or spill (r8) a 48-coord live set no matter what
// launch bounds say. So: 1024 threads x 8 points/thread -> live set =
// 24 coords + 8 dists + temps ~= 55 VGPR, UNDER the 64-VGPR operating
// point. The no-op asm makes remat impossible; the small live set makes
// spilling unprofitable. 16 waves reduce via LDS float4 slots, 1 barrier.
#define FPS_UPD(J)                                                             \
  do {                                                                         \
    float dx_ = __fsub_rn(px##J, qx);                                          \
    float dy_ = __fsub_rn(py##J, qy);                                          \
    float dz_ = __fsub_rn(pz##J, qz);                                          \
    float s_ = __fadd_rn(__fadd_rn(__fmul_rn(dx_, dx_), __fmul_rn(dy_, dy_)),  \
                         __fmul_rn(dz_, dz_));                                 \
    d##J = fminf(d##J, s_);                                                    \
  } while (0)

#define FPS_CHK(J)                                                             \
  if (d##J == wmax) { bi = J; wx = px##J; wy = py##J; wz = pz##J; }

#define FPS_SCAN(W, EXPR)                                                      \
  do { float e_ = (EXPR); if (e_ > bd) { bd = e_; bw = W; } } while (0)

__global__ __launch_bounds__(1024, 4) void k_fps(const float* __restrict__ xyz,
                                                 float* __restrict__ out_xyz,
                                                 float* __restrict__ out_idx) {
  const int b = blockIdx.x;
  const int t = threadIdx.x;
  const float* xb = xyz + (size_t)b * NPB * 3;

  // thread t owns points [t*8, t*8+8): 24 floats = 6 float4 loads
  const float4* gp = reinterpret_cast<const float4*>(xb + (size_t)t * 24);
  float4 v0 = gp[0], v1 = gp[1], v2 = gp[2];
  float4 v3 = gp[3], v4 = gp[4], v5 = gp[5];
  float px0 = v0.x, py0 = v0.y, pz0 = v0.z;
  float px1 = v0.w, py1 = v1.x, pz1 = v1.y;
  float px2 = v1.z, py2 = v1.w, pz2 = v2.x;
  float px3 = v2.y, py3 = v2.z, pz3 = v2.w;
  float px4 = v3.x, py4 = v3.y, pz4 = v3.z;
  float px5 = v3.w, py5 = v4.x, pz5 = v4.y;
  float px6 = v4.z, py6 = v4.w, pz6 = v5.x;
  float px7 = v5.y, py7 = v5.z, pz7 = v5.w;

  // Opaque-ify: defs become asm outputs -> rematerialization impossible.
  asm volatile("" : "+v"(px0), "+v"(py0), "+v"(pz0), "+v"(px1), "+v"(py1),
                    "+v"(pz1), "+v"(px2), "+v"(py2));
  asm volatile("" : "+v"(pz2), "+v"(px3), "+v"(py3), "+v"(pz3), "+v"(px4),
                    "+v"(py4), "+v"(pz4), "+v"(px5));
  asm volatile("" : "+v"(py5), "+v"(pz5), "+v"(px6), "+v"(py6), "+v"(pz6),
                    "+v"(px7), "+v"(py7), "+v"(pz7));

  float d0 = 1e10f, d1 = 1e10f, d2 = 1e10f, d3 = 1e10f;
  float d4 = 1e10f, d5 = 1e10f, d6 = 1e10f, d7 = 1e10f;

  __shared__ __align__(16) float sD[2][16];
  __shared__ __align__(16) float4 sWin[2][16];  // {x, y, z, idx}

  const int wid = t >> 6;
  const int lane = t & 63;

  float qx = xb[0], qy = xb[1], qz = xb[2];  // selection 0 = index 0
  if (t == 0) {
    out_idx[b * NPOINT + 0] = 0.0f;
    size_t o = (size_t)(b * NPOINT) * 3;
    out_xyz[o + 0] = qx; out_xyz[o + 1] = qy; out_xyz[o + 2] = qz;
  }

  for (int it = 1; it < NPOINT; ++it) {
    FPS_UPD(0); FPS_UPD(1); FPS_UPD(2); FPS_UPD(3);
    FPS_UPD(4); FPS_UPD(5); FPS_UPD(6); FPS_UPD(7);
    // per-thread max (v_max3-friendly tree)
    float m01 = fmaxf(d0, d1), m23 = fmaxf(d2, d3);
    float m45 = fmaxf(d4, d5), m67 = fmaxf(d6, d7);
    float best = fmaxf(fmaxf(m01, m23), fmaxf(m45, m67));
    // wave-level max
    float wmax = best;
#pragma unroll
    for (int off = 32; off >= 1; off >>= 1) wmax = fmaxf(wmax, __shfl_xor(wmax, off));
    const unsigned long long m = __ballot(best == wmax);
    const int p = it & 1;
    if (lane == (int)(__ffsll((unsigned long long)m) - 1)) {  // lowest tied lane
      // smallest local index equal to wmax (descending overrides)
      int bi = 7; float wx = px7, wy = py7, wz = pz7;
      FPS_CHK(6) FPS_CHK(5) FPS_CHK(4) FPS_CHK(3)
      FPS_CHK(2) FPS_CHK(1) FPS_CHK(0)
      sD[p][wid] = wmax;
      sWin[p][wid] = make_float4(wx, wy, wz, (float)(t * 8 + bi));
    }
    __syncthreads();  // the only barrier per iteration
    // every thread scans the 16 wave winners (broadcast LDS reads);
    // ordered strict > => smallest wid (= smallest index) wins ties
    const float4* sd4 = reinterpret_cast<const float4*>(&sD[p][0]);
    float4 a0 = sd4[0], a1 = sd4[1], a2 = sd4[2], a3 = sd4[3];
    float bd = a0.x;
    int bw = 0;
    FPS_SCAN(1, a0.y);  FPS_SCAN(2, a0.z);  FPS_SCAN(3, a0.w);
    FPS_SCAN(4, a1.x);  FPS_SCAN(5, a1.y);  FPS_SCAN(6, a1.z);  FPS_SCAN(7, a1.w);
    FPS_SCAN(8, a2.x);  FPS_SCAN(9, a2.y);  FPS_SCAN(10, a2.z); FPS_SCAN(11, a2.w);
    FPS_SCAN(12, a3.x); FPS_SCAN(13, a3.y); FPS_SCAN(14, a3.z); FPS_SCAN(15, a3.w);
    float4 win = sWin[p][bw];
    qx = win.x; qy = win.y; qz = win.z;
    if (t == 0) {
      out_idx[b * NPOINT + it] = win.w;
      size_t o = (size_t)(b * NPOINT + it) * 3;
      out_xyz[o + 0] = qx; out_xyz[o + 1] = qy; out_xyz[o + 2] = qz;
    }
  }
}

// ---------------------------------------------------------- feature transpose
// features f32 [64][Ntot] -> feat_t bf16 [Ntot][64]
__global__ __launch_bounds__(256) void k_transpose(const float* __restrict__ in,
                                                   unsigned short* __restrict__ out,
                                                   int Ntot) {
  __shared__ __align__(16) unsigned short tile[64][65];
  const int t = threadIdx.x;
  const int n0 = blockIdx.x * 64;
#pragma unroll
  for (int i = 0; i < 16; ++i) {
    int c = i * 4 + (t >> 6);
    int n = t & 63;
    tile[c][n] = f2bf(in[(size_t)c * Ntot + n0 + n]);
  }
  __syncthreads();
#pragma unroll
  for (int i = 0; i < 16; ++i) {
    int n = i * 4 + (t >> 6);
    int c = t & 63;
    out[(size_t)(n0 + n) * 64 + c] = tile[c][n];
  }
}

// ---------------------------------------------------------------- ball query
// One wave per center (8 waves/block). Fixed 64 rounds x 2 points/lane so
// loads pipeline across rounds. Ordered compaction via ballot+popcount.
__global__ __launch_bounds__(512) void k_ball(const float* __restrict__ xyz,
                                              const float* __restrict__ fps_idx_f,
                                              float* __restrict__ sids_f) {
  __shared__ int slots[8 * NSAMPLE];
  const int b = blockIdx.x >> 6;
  const int cbase = (blockIdx.x & 63) * 8;
  const int t = threadIdx.x;
  const float* xb = xyz + (size_t)b * NPB * 3;

  const int w = t >> 6, lane = t & 63;
  const int c_local = cbase + w;
  const int ci = (int)fps_idx_f[b * NPOINT + c_local];
  const float cx = xb[ci * 3 + 0];
  const float cy = xb[ci * 3 + 1];
  const float cz = xb[ci * 3 + 2];
  const float R2 = 0.01f;  // f32(0.1*0.1), numpy weak-scalar promotion
  const unsigned long long below = (1ull << lane) - 1ull;

  int cnt = 0;
#pragma unroll 4
  for (int r = 0; r < 64; ++r) {
    const int p0 = r * 128 + lane;
    const int p1 = p0 + 64;
    float ax = xb[p0 * 3 + 0], ay = xb[p0 * 3 + 1], az = xb[p0 * 3 + 2];
    float bx = xb[p1 * 3 + 0], by = xb[p1 * 3 + 1], bz = xb[p1 * 3 + 2];
    float dxa = __fsub_rn(ax, cx), dya = __fsub_rn(ay, cy), dza = __fsub_rn(az, cz);
    float dxb = __fsub_rn(bx, cx), dyb = __fsub_rn(by, cy), dzb = __fsub_rn(bz, cz);
    float d2a = __fadd_rn(__fadd_rn(__fmul_rn(dxa, dxa), __fmul_rn(dya, dya)), __fmul_rn(dza, dza));
    float d2b = __fadd_rn(__fadd_rn(__fmul_rn(dxb, dxb), __fmul_rn(dyb, dyb)), __fmul_rn(dzb, dzb));
    const bool i0 = d2a < R2;
    const bool i1 = d2b < R2;
    const unsigned long long m0 = __ballot(i0);
    if (i0) {
      int pos = cnt + (int)__popcll(m0 & below);
      if (pos < NSAMPLE) slots[w * NSAMPLE + pos] = p0;
    }
    cnt += (int)__popcll(m0);
    const unsigned long long m1 = __ballot(i1);
    if (i1) {
      int pos = cnt + (int)__popcll(m1 & below);
      if (pos < NSAMPLE) slots[w * NSAMPLE + pos] = p1;
    }
    cnt += (int)__popcll(m1);
  }
  if (lane < NSAMPLE) {
    const int first = (cnt > 0) ? slots[w * NSAMPLE] : 0;
    const int v = (lane < cnt) ? slots[w * NSAMPLE + lane] : first;
    sids_f[((size_t)(b * NPOINT + c_local)) * NSAMPLE + lane] = (float)v;
  }
}

// ------------------------------------------------------- gather + MLP + max
// 32 lanes = 32 samples, 2 centers per wave, 8 centers per 256-thr block.
// W0/W2 f32 in LDS, W1 bf16 in LDS (~59 KB). h1/h2 in registers.
__global__ __launch_bounds__(256) void k_mlp(const float* __restrict__ xyz,
                                             const float* __restrict__ feat,
                                             const unsigned short* __restrict__ feat_t,
                                             const float* __restrict__ fps_idx_f,
                                             const float* __restrict__ sids_f,
                                             const float* __restrict__ w0g,
                                             const float* __restrict__ b0g,
                                             const float* __restrict__ w1g,
                                             const float* __restrict__ b1g,
                                             const float* __restrict__ w2g,
                                             const float* __restrict__ b2g,
                                             float* __restrict__ out_feat,
                                             int Ntot, int useT) {
  __shared__ __align__(16) float W0s[64 * 68];            // padded rows (c 67 = 0)
  __shared__ __align__(16) unsigned short W1s[64 * 64];   // bf16
  __shared__ __align__(16) float W2s[128 * 64];
  __shared__ float b0s[64], b1s[64], b2s[128];
  const int t = threadIdx.x;
  for (int i = t; i < 64 * 68; i += 256) {
    int r = i / 68, c = i - r * 68;
    W0s[i] = (c < 67) ? w0g[r * 67 + c] : 0.0f;
  }
  for (int i = t; i < 64 * 64; i += 256) W1s[i] = f2bf(w1g[i]);
  for (int i = t; i < 128 * 64; i += 256) W2s[i] = w2g[i];
  if (t < 64) b0s[t] = b0g[t];
  if (t < 64) b1s[t] = b1g[t];
  if (t < 128) b2s[t] = b2g[t];
  __syncthreads();

  const int b = blockIdx.x >> 6;
  const int c_local = (blockIdx.x & 63) * 8 + (t >> 5);
  const int s = t & 31;
  const int ci = (int)fps_idx_f[b * NPOINT + c_local];
  const float cx = xyz[((size_t)b * NPB + ci) * 3 + 0];
  const float cy = xyz[((size_t)b * NPB + ci) * 3 + 1];
  const float cz = xyz[((size_t)b * NPB + ci) * 3 + 2];
  const int id = (int)sids_f[((size_t)(b * NPOINT + c_local)) * NSAMPLE + s];

  float g[68];
  {
    const size_t pb = ((size_t)b * NPB + id) * 3;
    g[0] = __fsub_rn(xyz[pb + 0], cx);
    g[1] = __fsub_rn(xyz[pb + 1], cy);
    g[2] = __fsub_rn(xyz[pb + 2], cz);
    if (useT) {
      const uint4* fp = reinterpret_cast<const uint4*>(feat_t + ((size_t)b * NPB + id) * 64);
#pragma unroll
      for (int v = 0; v < 8; ++v) {
        uint4 r = fp[v];
        unsigned int vs[4] = {r.x, r.y, r.z, r.w};
#pragma unroll
        for (int q = 0; q < 4; ++q) {
          g[3 + v * 8 + q * 2 + 0] = __uint_as_float(vs[q] << 16);
          g[3 + v * 8 + q * 2 + 1] = __uint_as_float(vs[q] & 0xFFFF0000u);
        }
      }
    } else {
      const float* col = feat + (size_t)(b * NPB + id);
#pragma unroll 8
      for (int c = 0; c < 64; ++c) g[3 + c] = col[(size_t)c * Ntot];
    }
    g[67] = 0.0f;
  }

  float h1[64];
#pragma unroll
  for (int o = 0; o < 64; ++o) {
    float acc = b0s[o];
    const float4* wp = reinterpret_cast<const float4*>(&W0s[o * 68]);
#pragma unroll
    for (int c4 = 0; c4 < 17; ++c4) {
      float4 wv = wp[c4];
      acc += wv.x * g[c4 * 4 + 0];
      acc += wv.y * g[c4 * 4 + 1];
      acc += wv.z * g[c4 * 4 + 2];
      acc += wv.w * g[c4 * 4 + 3];
    }
    h1[o] = fmaxf(acc, 0.0f);
  }
  float h2[64];
#pragma unroll
  for (int o = 0; o < 64; ++o) {
    float acc = b1s[o];
    const uint2* wp = reinterpret_cast<const uint2*>(&W1s[o * 64]);
#pragma unroll
    for (int c4 = 0; c4 < 16; ++c4) {
      uint2 u = wp[c4];
      acc += __uint_as_float(u.x << 16) * h1[c4 * 4 + 0];
      acc += __uint_as_float(u.x & 0xFFFF0000u) * h1[c4 * 4 + 1];
      acc += __uint_as_float(u.y << 16) * h1[c4 * 4 + 2];
      acc += __uint_as_float(u.y & 0xFFFF0000u) * h1[c4 * 4 + 3];
    }
    h2[o] = fmaxf(acc, 0.0f);
  }
#pragma unroll 1
  for (int o = 0; o < 128; ++o) {
    float acc = b2s[o];
    const float4* wp = reinterpret_cast<const float4*>(&W2s[o * 64]);
#pragma unroll
    for (int c4 = 0; c4 < 16; ++c4) {
      float4 wv = wp[c4];
      acc += wv.x * h2[c4 * 4 + 0];
      acc += wv.y * h2[c4 * 4 + 1];
      acc += wv.z * h2[c4 * 4 + 2];
      acc += wv.w * h2[c4 * 4 + 3];
    }
    float v = fmaxf(acc, 0.0f);
#pragma unroll
    for (int off = 16; off >= 1; off >>= 1) v = fmaxf(v, __shfl_xor(v, off));
    if (s == 0) out_feat[((size_t)b * 128 + o) * NPOINT + c_local] = v;
  }
}

// ------------------------------------------------------------------- launch
extern "C" void kernel_launch(void* const* d_in, const int* in_sizes, int n_in,
                              void* d_out, int out_size, void* d_ws, size_t ws_size,
                              hipStream_t stream) {
  (void)n_in; (void)out_size;
  const float* xyz = (const float*)d_in[0];
  const float* feat = (const float*)d_in[1];
  // d_in[2] = num_points (8192, fixed by setup)
  const float* w0 = (const float*)d_in[3];
  const float* b0 = (const float*)d_in[4];
  const float* w1 = (const float*)d_in[5];
  const float* b1 = (const float*)d_in[6];
  const float* w2 = (const float*)d_in[7];
  const float* b2 = (const float*)d_in[8];

  const int Ntot = in_sizes[0] / 3;   // 65536
  const int B = Ntot / NPB;           // 8

  float* out = (float*)d_out;
  float* o_xyz = out;                                    // [B,512,3]
  float* o_idx = o_xyz + (size_t)B * NPOINT * 3;         // [B,512]
  float* o_feat = o_idx + (size_t)B * NPOINT;            // [B,128,512]
  float* o_sids = o_feat + (size_t)B * 128 * NPOINT;     // [B,512,32]

  // Workspace: only the transposed-features buffer (bf16), only if it fits.
  const size_t ft_bytes = (size_t)Ntot * 64 * 2;         // 8 MB
  const int useT = (ws_size >= ft_bytes) ? 1 : 0;
  unsigned short* ft_ws = (unsigned short*)d_ws;

  if (useT) {
    k_transpose<<<dim3(Ntot / 64), dim3(256), 0, stream>>>(feat, ft_ws, Ntot);
  }
  k_fps<<<dim3(B), dim3(1024), 0, stream>>>(xyz, o_xyz, o_idx);
  k_ball<<<dim3(B * 64), dim3(512), 0, stream>>>(xyz, o_idx, o_sids);
  k_mlp<<<dim3(B * 64), dim3(256), 0, stream>>>(xyz, feat, ft_ws, o_idx, o_sids,
                                                w0, b0, w1, b1, w2, b2, o_feat,
                                                Ntot, useT);
}

// Round 10
// 900.757 us; speedup vs baseline: 1.0397x; 1.0397x over previous
//
#include <hip/hip_runtime.h>
#include <cstdint>
#include <cstddef>

#define NPOINT 512
#define NSAMPLE 32
#define NPB 8192  // points per batch

typedef float f32x2 __attribute__((ext_vector_type(2)));

// Inputs: float32. Outputs: float32 flat concat (new_xyz, new_idx,
// new_features, sample_ids). Selection math (FPS argmax, ball d2<r2) must be
// bit-exact vs numpy f32: RN ops, no FMA contraction, exact tie-breaks.
__device__ __forceinline__ unsigned short f2bf(float f) {
  unsigned int u = __float_as_uint(f);
  unsigned int r = u + 0x7FFFu + ((u >> 16) & 1u);  // RNE
  return (unsigned short)(r >> 16);
}

// gfx9 wave64 max-reduce via DPP (row_shr 1/2/4/8, row_bcast15/31), result
// broadcast from lane 63. Identity 0.0f is safe: all dists >= 0.
__device__ __forceinline__ float wave_max_f32(float x) {
  int t;
  t = __builtin_amdgcn_update_dpp(0, __float_as_int(x), 0x111, 0xf, 0xf, false);
  x = fmaxf(x, __int_as_float(t));
  t = __builtin_amdgcn_update_dpp(0, __float_as_int(x), 0x112, 0xf, 0xf, false);
  x = fmaxf(x, __int_as_float(t));
  t = __builtin_amdgcn_update_dpp(0, __float_as_int(x), 0x114, 0xf, 0xf, false);
  x = fmaxf(x, __int_as_float(t));
  t = __builtin_amdgcn_update_dpp(0, __float_as_int(x), 0x118, 0xf, 0xf, false);
  x = fmaxf(x, __int_as_float(t));
  t = __builtin_amdgcn_update_dpp(0, __float_as_int(x), 0x142, 0xa, 0xf, false);
  x = fmaxf(x, __int_as_float(t));
  t = __builtin_amdgcn_update_dpp(0, __float_as_int(x), 0x143, 0xc, 0xf, false);
  x = fmaxf(x, __int_as_float(t));
  return __int_as_float(__builtin_amdgcn_readlane(__float_as_int(x), 63));
}

// ---------------------------------------------------------------- FPS
// 1024 thr x 8 points/thread (r9 skeleton: VGPR=40, no spill). This round:
// packed-f32 distance update (v_pk_add/mul via float2 ext-vectors, fp
// contract OFF for numpy-exact ((x^2+y^2)+z^2) rounding) and DPP wave-max
// (replaces 6 ds-shuffle levels, ~240cyc -> ~25cyc). One barrier/iter,
// parity-buffered LDS slots, strict tie-breaks (lowest lane / lowest wid).
__global__ __launch_bounds__(1024, 4) void k_fps(const float* __restrict__ xyz,
                                                 float* __restrict__ out_xyz,
                                                 float* __restrict__ out_idx) {
#pragma clang fp contract(off)
  const int b = blockIdx.x;
  const int t = threadIdx.x;
  const float* xb = xyz + (size_t)b * NPB * 3;

  // thread t owns points [t*8, t*8+8): 24 floats = 6 float4 loads
  const float4* gp = reinterpret_cast<const float4*>(xb + (size_t)t * 24);
  float4 v0 = gp[0], v1 = gp[1], v2 = gp[2];
  float4 v3 = gp[3], v4 = gp[4], v5 = gp[5];
  // pack as pairs: group G covers points {2G, 2G+1}
  f32x2 pX0 = {v0.x, v0.w}, pY0 = {v0.y, v1.x}, pZ0 = {v0.z, v1.y};
  f32x2 pX1 = {v1.z, v2.y}, pY1 = {v1.w, v2.z}, pZ1 = {v2.x, v2.w};
  f32x2 pX2 = {v3.x, v3.w}, pY2 = {v3.y, v4.x}, pZ2 = {v3.z, v4.y};
  f32x2 pX3 = {v4.z, v5.y}, pY3 = {v4.w, v5.z}, pZ3 = {v5.x, v5.w};

  // Opaque-ify (defs become asm outputs -> remat from memory impossible)
  asm volatile("" : "+v"(pX0), "+v"(pY0), "+v"(pZ0), "+v"(pX1), "+v"(pY1), "+v"(pZ1));
  asm volatile("" : "+v"(pX2), "+v"(pY2), "+v"(pZ2), "+v"(pX3), "+v"(pY3), "+v"(pZ3));

  float d0 = 1e10f, d1 = 1e10f, d2 = 1e10f, d3 = 1e10f;
  float d4 = 1e10f, d5 = 1e10f, d6 = 1e10f, d7 = 1e10f;

  __shared__ __align__(16) float sD[2][16];
  __shared__ __align__(16) float4 sWin[2][16];  // {x, y, z, idx}

  const int wid = t >> 6;
  const int lane = t & 63;

  float qx = xb[0], qy = xb[1], qz = xb[2];  // selection 0 = index 0
  if (t == 0) {
    out_idx[b * NPOINT + 0] = 0.0f;
    size_t o = (size_t)(b * NPOINT) * 3;
    out_xyz[o + 0] = qx; out_xyz[o + 1] = qy; out_xyz[o + 2] = qz;
  }

  for (int it = 1; it < NPOINT; ++it) {
    const f32x2 nqx = {-qx, -qx}, nqy = {-qy, -qy}, nqz = {-qz, -qz};
    // exact update: dx=px+(-qx) [== px-qx exactly]; ((dx^2+dy^2)+dz^2), all RN
#define UPD2(G, A, B)                                                          \
    do {                                                                       \
      f32x2 dx_ = pX##G + nqx;                                                 \
      f32x2 dy_ = pY##G + nqy;                                                 \
      f32x2 dz_ = pZ##G + nqz;                                                 \
      f32x2 s_ = dx_ * dx_ + dy_ * dy_;                                        \
      s_ = s_ + dz_ * dz_;                                                     \
      d##A = fminf(d##A, s_.x);                                                \
      d##B = fminf(d##B, s_.y);                                                \
    } while (0)
    UPD2(0, 0, 1); UPD2(1, 2, 3); UPD2(2, 4, 5); UPD2(3, 6, 7);
#undef UPD2
    // per-thread max tree
    float m01 = fmaxf(d0, d1), m23 = fmaxf(d2, d3);
    float m45 = fmaxf(d4, d5), m67 = fmaxf(d6, d7);
    float best = fmaxf(fmaxf(m01, m23), fmaxf(m45, m67));
    // wave max via DPP + sgpr broadcast
    const float wmax = wave_max_f32(best);
    const unsigned long long m = __ballot(best == wmax);
    const int p = it & 1;
    if (lane == (int)(__ffsll((unsigned long long)m) - 1)) {  // lowest tied lane
      // smallest local index equal to wmax (descending overrides)
      int bi = 7; float wx = pX3.y, wy = pY3.y, wz = pZ3.y;
      if (d6 == wmax) { bi = 6; wx = pX3.x; wy = pY3.x; wz = pZ3.x; }
      if (d5 == wmax) { bi = 5; wx = pX2.y; wy = pY2.y; wz = pZ2.y; }
      if (d4 == wmax) { bi = 4; wx = pX2.x; wy = pY2.x; wz = pZ2.x; }
      if (d3 == wmax) { bi = 3; wx = pX1.y; wy = pY1.y; wz = pZ1.y; }
      if (d2 == wmax) { bi = 2; wx = pX1.x; wy = pY1.x; wz = pZ1.x; }
      if (d1 == wmax) { bi = 1; wx = pX0.y; wy = pY0.y; wz = pZ0.y; }
      if (d0 == wmax) { bi = 0; wx = pX0.x; wy = pY0.x; wz = pZ0.x; }
      sD[p][wid] = wmax;
      sWin[p][wid] = make_float4(wx, wy, wz, (float)(t * 8 + bi));
    }
    __syncthreads();  // the only barrier per iteration
    // every thread scans the 16 wave winners; strict > => smallest wid wins
    const float4* sd4 = reinterpret_cast<const float4*>(&sD[p][0]);
    float4 a0 = sd4[0], a1 = sd4[1], a2 = sd4[2], a3 = sd4[3];
    float bd = a0.x;
    int bw = 0;
#define SCAN(W, E) do { float e_ = (E); if (e_ > bd) { bd = e_; bw = W; } } while (0)
    SCAN(1, a0.y);  SCAN(2, a0.z);  SCAN(3, a0.w);
    SCAN(4, a1.x);  SCAN(5, a1.y);  SCAN(6, a1.z);  SCAN(7, a1.w);
    SCAN(8, a2.x);  SCAN(9, a2.y);  SCAN(10, a2.z); SCAN(11, a2.w);
    SCAN(12, a3.x); SCAN(13, a3.y); SCAN(14, a3.z); SCAN(15, a3.w);
#undef SCAN
    float4 win = sWin[p][bw];
    qx = win.x; qy = win.y; qz = win.z;
    if (t == 0) {
      out_idx[b * NPOINT + it] = win.w;
      size_t o = (size_t)(b * NPOINT + it) * 3;
      out_xyz[o + 0] = qx; out_xyz[o + 1] = qy; out_xyz[o + 2] = qz;
    }
  }
}

// ---------------------------------------------------------- feature transpose
// features f32 [64][Ntot] -> feat_t bf16 [Ntot][64]
__global__ __launch_bounds__(256) void k_transpose(const float* __restrict__ in,
                                                   unsigned short* __restrict__ out,
                                                   int Ntot) {
  __shared__ __align__(16) unsigned short tile[64][65];
  const int t = threadIdx.x;
  const int n0 = blockIdx.x * 64;
#pragma unroll
  for (int i = 0; i < 16; ++i) {
    int c = i * 4 + (t >> 6);
    int n = t & 63;
    tile[c][n] = f2bf(in[(size_t)c * Ntot + n0 + n]);
  }
  __syncthreads();
#pragma unroll
  for (int i = 0; i < 16; ++i) {
    int n = i * 4 + (t >> 6);
    int c = t & 63;
    out[(size_t)(n0 + n) * 64 + c] = tile[c][n];
  }
}

// ---------------------------------------------------------------- ball query
// One wave per center (8 waves/block). Fixed 64 rounds x 2 points/lane so
// loads pipeline across rounds. Ordered compaction via ballot+popcount.
__global__ __launch_bounds__(512) void k_ball(const float* __restrict__ xyz,
                                              const float* __restrict__ fps_idx_f,
                                              float* __restrict__ sids_f) {
  __shared__ int slots[8 * NSAMPLE];
  const int b = blockIdx.x >> 6;
  const int cbase = (blockIdx.x & 63) * 8;
  const int t = threadIdx.x;
  const float* xb = xyz + (size_t)b * NPB * 3;

  const int w = t >> 6, lane = t & 63;
  const int c_local = cbase + w;
  const int ci = (int)fps_idx_f[b * NPOINT + c_local];
  const float cx = xb[ci * 3 + 0];
  const float cy = xb[ci * 3 + 1];
  const float cz = xb[ci * 3 + 2];
  const float R2 = 0.01f;  // f32(0.1*0.1), numpy weak-scalar promotion
  const unsigned long long below = (1ull << lane) - 1ull;

  int cnt = 0;
#pragma unroll 4
  for (int r = 0; r < 64; ++r) {
    const int p0 = r * 128 + lane;
    const int p1 = p0 + 64;
    float ax = xb[p0 * 3 + 0], ay = xb[p0 * 3 + 1], az = xb[p0 * 3 + 2];
    float bx = xb[p1 * 3 + 0], by = xb[p1 * 3 + 1], bz = xb[p1 * 3 + 2];
    float dxa = __fsub_rn(ax, cx), dya = __fsub_rn(ay, cy), dza = __fsub_rn(az, cz);
    float dxb = __fsub_rn(bx, cx), dyb = __fsub_rn(by, cy), dzb = __fsub_rn(bz, cz);
    float d2a = __fadd_rn(__fadd_rn(__fmul_rn(dxa, dxa), __fmul_rn(dya, dya)), __fmul_rn(dza, dza));
    float d2b = __fadd_rn(__fadd_rn(__fmul_rn(dxb, dxb), __fmul_rn(dyb, dyb)), __fmul_rn(dzb, dzb));
    const bool i0 = d2a < R2;
    const bool i1 = d2b < R2;
    const unsigned long long m0 = __ballot(i0);
    if (i0) {
      int pos = cnt + (int)__popcll(m0 & below);
      if (pos < NSAMPLE) slots[w * NSAMPLE + pos] = p0;
    }
    cnt += (int)__popcll(m0);
    const unsigned long long m1 = __ballot(i1);
    if (i1) {
      int pos = cnt + (int)__popcll(m1 & below);
      if (pos < NSAMPLE) slots[w * NSAMPLE + pos] = p1;
    }
    cnt += (int)__popcll(m1);
  }
  if (lane < NSAMPLE) {
    const int first = (cnt > 0) ? slots[w * NSAMPLE] : 0;
    const int v = (lane < cnt) ? slots[w * NSAMPLE + lane] : first;
    sids_f[((size_t)(b * NPOINT + c_local)) * NSAMPLE + lane] = (float)v;
  }
}

// ------------------------------------------------------- gather + MLP + max
// 32 lanes = 32 samples, 2 centers per wave, 8 centers per 256-thr block.
// W0/W2 f32 in LDS, W1 bf16 in LDS (~59 KB). h1/h2 in registers.
__global__ __launch_bounds__(256) void k_mlp(const float* __restrict__ xyz,
                                             const float* __restrict__ feat,
                                             const unsigned short* __restrict__ feat_t,
                                             const float* __restrict__ fps_idx_f,
                                             const float* __restrict__ sids_f,
                                             const float* __restrict__ w0g,
                                             const float* __restrict__ b0g,
                                             const float* __restrict__ w1g,
                                             const float* __restrict__ b1g,
                                             const float* __restrict__ w2g,
                                             const float* __restrict__ b2g,
                                             float* __restrict__ out_feat,
                                             int Ntot, int useT) {
  __shared__ __align__(16) float W0s[64 * 68];            // padded rows (c 67 = 0)
  __shared__ __align__(16) unsigned short W1s[64 * 64];   // bf16
  __shared__ __align__(16) float W2s[128 * 64];
  __shared__ float b0s[64], b1s[64], b2s[128];
  const int t = threadIdx.x;
  for (int i = t; i < 64 * 68; i += 256) {
    int r = i / 68, c = i - r * 68;
    W0s[i] = (c < 67) ? w0g[r * 67 + c] : 0.0f;
  }
  for (int i = t; i < 64 * 64; i += 256) W1s[i] = f2bf(w1g[i]);
  for (int i = t; i < 128 * 64; i += 256) W2s[i] = w2g[i];
  if (t < 64) b0s[t] = b0g[t];
  if (t < 64) b1s[t] = b1g[t];
  if (t < 128) b2s[t] = b2g[t];
  __syncthreads();

  const int b = blockIdx.x >> 6;
  const int c_local = (blockIdx.x & 63) * 8 + (t >> 5);
  const int s = t & 31;
  const int ci = (int)fps_idx_f[b * NPOINT + c_local];
  const float cx = xyz[((size_t)b * NPB + ci) * 3 + 0];
  const float cy = xyz[((size_t)b * NPB + ci) * 3 + 1];
  const float cz = xyz[((size_t)b * NPB + ci) * 3 + 2];
  const int id = (int)sids_f[((size_t)(b * NPOINT + c_local)) * NSAMPLE + s];

  float g[68];
  {
    const size_t pb = ((size_t)b * NPB + id) * 3;
    g[0] = __fsub_rn(xyz[pb + 0], cx);
    g[1] = __fsub_rn(xyz[pb + 1], cy);
    g[2] = __fsub_rn(xyz[pb + 2], cz);
    if (useT) {
      const uint4* fp = reinterpret_cast<const uint4*>(feat_t + ((size_t)b * NPB + id) * 64);
#pragma unroll
      for (int v = 0; v < 8; ++v) {
        uint4 r = fp[v];
        unsigned int vs[4] = {r.x, r.y, r.z, r.w};
#pragma unroll
        for (int q = 0; q < 4; ++q) {
          g[3 + v * 8 + q * 2 + 0] = __uint_as_float(vs[q] << 16);
          g[3 + v * 8 + q * 2 + 1] = __uint_as_float(vs[q] & 0xFFFF0000u);
        }
      }
    } else {
      const float* col = feat + (size_t)(b * NPB + id);
#pragma unroll 8
      for (int c = 0; c < 64; ++c) g[3 + c] = col[(size_t)c * Ntot];
    }
    g[67] = 0.0f;
  }

  float h1[64];
#pragma unroll
  for (int o = 0; o < 64; ++o) {
    float acc = b0s[o];
    const float4* wp = reinterpret_cast<const float4*>(&W0s[o * 68]);
#pragma unroll
    for (int c4 = 0; c4 < 17; ++c4) {
      float4 wv = wp[c4];
      acc += wv.x * g[c4 * 4 + 0];
      acc += wv.y * g[c4 * 4 + 1];
      acc += wv.z * g[c4 * 4 + 2];
      acc += wv.w * g[c4 * 4 + 3];
    }
    h1[o] = fmaxf(acc, 0.0f);
  }
  float h2[64];
#pragma unroll
  for (int o = 0; o < 64; ++o) {
    float acc = b1s[o];
    const uint2* wp = reinterpret_cast<const uint2*>(&W1s[o * 64]);
#pragma unroll
    for (int c4 = 0; c4 < 16; ++c4) {
      uint2 u = wp[c4];
      acc += __uint_as_float(u.x << 16) * h1[c4 * 4 + 0];
      acc += __uint_as_float(u.x & 0xFFFF0000u) * h1[c4 * 4 + 1];
      acc += __uint_as_float(u.y << 16) * h1[c4 * 4 + 2];
      acc += __uint_as_float(u.y & 0xFFFF0000u) * h1[c4 * 4 + 3];
    }
    h2[o] = fmaxf(acc, 0.0f);
  }
#pragma unroll 1
  for (int o = 0; o < 128; ++o) {
    float acc = b2s[o];
    const float4* wp = reinterpret_cast<const float4*>(&W2s[o * 64]);
#pragma unroll
    for (int c4 = 0; c4 < 16; ++c4) {
      float4 wv = wp[c4];
      acc += wv.x * h2[c4 * 4 + 0];
      acc += wv.y * h2[c4 * 4 + 1];
      acc += wv.z * h2[c4 * 4 + 2];
      acc += wv.w * h2[c4 * 4 + 3];
    }
    float v = fmaxf(acc, 0.0f);
#pragma unroll
    for (int off = 16; off >= 1; off >>= 1) v = fmaxf(v, __shfl_xor(v, off));
    if (s == 0) out_feat[((size_t)b * 128 + o) * NPOINT + c_local] = v;
  }
}

// ------------------------------------------------------------------- launch
extern "C" void kernel_launch(void* const* d_in, const int* in_sizes, int n_in,
                              void* d_out, int out_size, void* d_ws, size_t ws_size,
                              hipStream_t stream) {
  (void)n_in; (void)out_size;
  const float* xyz = (const float*)d_in[0];
  const float* feat = (const float*)d_in[1];
  // d_in[2] = num_points (8192, fixed by setup)
  const float* w0 = (const float*)d_in[3];
  const float* b0 = (const float*)d_in[4];
  const float* w1 = (const float*)d_in[5];
  const float* b1 = (const float*)d_in[6];
  const float* w2 = (const float*)d_in[7];
  const float* b2 = (const float*)d_in[8];

  const int Ntot = in_sizes[0] / 3;   // 65536
  const int B = Ntot / NPB;           // 8

  float* out = (float*)d_out;
  float* o_xyz = out;                                    // [B,512,3]
  float* o_idx = o_xyz + (size_t)B * NPOINT * 3;         // [B,512]
  float* o_feat = o_idx + (size_t)B * NPOINT;            // [B,128,512]
  float* o_sids = o_feat + (size_t)B * 128 * NPOINT;     // [B,512,32]

  // Workspace: only the transposed-features buffer (bf16), only if it fits.
  const size_t ft_bytes = (size_t)Ntot * 64 * 2;         // 8 MB
  const int useT = (ws_size >= ft_bytes) ? 1 : 0;
  unsigned short* ft_ws = (unsigned short*)d_ws;

  if (useT) {
    k_transpose<<<dim3(Ntot / 64), dim3(256), 0, stream>>>(feat, ft_ws, Ntot);
  }
  k_fps<<<dim3(B), dim3(1024), 0, stream>>>(xyz, o_xyz, o_idx);
  k_ball<<<dim3(B * 64), dim3(512), 0, stream>>>(xyz, o_idx, o_sids);
  k_mlp<<<dim3(B * 64), dim3(256), 0, stream>>>(xyz, feat, ft_ws, o_idx, o_sids,
                                                w0, b0, w1, b1, w2, b2, o_feat,
                                                Ntot, useT);
}